// Round 8
// baseline (412.436 us; speedup 1.0000x reference)
//
#include <hip/hip_runtime.h>
#include <stdint.h>

typedef __bf16 bf16_t;
typedef __bf16 bf16x8 __attribute__((ext_vector_type(8)));
typedef float f32x4 __attribute__((ext_vector_type(4)));

static __device__ __forceinline__ float bflo(uint32_t v){ union{uint32_t u; float f;} c; c.u = v<<16; return c.f; }
static __device__ __forceinline__ float bfhi(uint32_t v){ union{uint32_t u; float f;} c; c.u = v & 0xffff0000u; return c.f; }

#define BKBITS 7           // 128 nodes per bucket
#define MAXBK  1024        // supports NN <= 131072
#define BKCAP  3072        // slots per bucket (mean 2046, sd 45 -> +22 sd headroom)

__global__ void k_zero_i(int* __restrict__ p, int n){
  int i = blockIdx.x*256 + threadIdx.x;
  if(i < n) p[i] = 0;
}

// CSR build pass 1: bucket-binning. Per-block LDS histogram over dst>>7 buckets,
// ONE global atomic per (block,bucket) to reserve a range (200K fabric atomics
// instead of 1.6M - R5 lesson: fabric atomic-with-return caps at ~24 G/s),
// then LDS-cursor scatter of packed (src | dst_local<<20) into bucket segments.
__global__ __launch_bounds__(1024) void k_bin(const int* __restrict__ ei, int E, int nbk,
                                              int* __restrict__ bucketCursorP,
                                              uint32_t* __restrict__ pairs){
  __shared__ int hist[MAXBK];
  __shared__ int cur[MAXBK];
  int nb = gridDim.x;
  int per = (E + nb - 1) / nb;
  int e0 = blockIdx.x * per;
  int e1 = e0 + per; if(e1 > E) e1 = E;
  for(int i = threadIdx.x; i < nbk; i += 1024) hist[i] = 0;
  __syncthreads();
  for(int e = e0 + threadIdx.x; e < e1; e += 1024)
    atomicAdd(&hist[ei[E + e] >> BKBITS], 1);
  __syncthreads();
  for(int i = threadIdx.x; i < nbk; i += 1024){
    int h = hist[i];
    int base = h ? atomicAdd(&bucketCursorP[i << 4], h) : 0;
    cur[i] = i * BKCAP + base;
  }
  __syncthreads();
  for(int e = e0 + threadIdx.x; e < e1; e += 1024){
    int s = ei[e], d = ei[E + e];
    int b = d >> BKBITS;
    int pos = atomicAdd(&cur[b], 1);
    if(pos < (b + 1) * BKCAP)
      pairs[pos] = (uint32_t)s | ((uint32_t)(d & ((1<<BKBITS)-1)) << 20);
  }
}

// exclusive scan of bucket totals (padded cursors) -> bucketBase
__global__ __launch_bounds__(1024) void k_scan_bkt(const int* __restrict__ bucketCursorP,
                                                   int* __restrict__ bucketBase, int nbk){
  __shared__ int s[1024];
  int tid = threadIdx.x;
  int v = (tid < nbk) ? bucketCursorP[tid << 4] : 0;
  s[tid] = v; __syncthreads();
  #pragma unroll
  for(int d = 1; d < 1024; d <<= 1){
    int t = (tid >= d) ? s[tid-d] : 0;
    __syncthreads();
    s[tid] += t;
    __syncthreads();
  }
  if(tid < nbk) bucketBase[tid] = s[tid] - v;
}

// CSR build pass 2: one block per bucket. LDS count over 128 local nodes,
// LDS scan -> global offsets/counts/dinv, LDS-cursor scatter -> csr_src.
// All per-edge atomics are LDS. Output format identical to the old CSR.
__global__ __launch_bounds__(256) void k_fine(const uint32_t* __restrict__ pairs,
                                              const int* __restrict__ bucketCursorP,
                                              const int* __restrict__ bucketBase,
                                              int* __restrict__ counts_c,
                                              int* __restrict__ offsets,
                                              float* __restrict__ dinv,
                                              int* __restrict__ csr_src, int n){
  __shared__ int cnt[128];
  __shared__ int off[128];
  int b = blockIdx.x;
  int cn = bucketCursorP[b << 4]; if(cn > BKCAP) cn = BKCAP;
  int base = bucketBase[b];
  const uint32_t* p = pairs + (long)b * BKCAP;
  int tid = threadIdx.x;
  if(tid < 128) cnt[tid] = 0;
  __syncthreads();
  for(int i = tid; i < cn; i += 256)
    atomicAdd(&cnt[p[i] >> 20], 1);
  __syncthreads();
  int v = (tid < 128) ? cnt[tid] : 0;
  if(tid < 128) off[tid] = v;
  __syncthreads();
  #pragma unroll
  for(int d = 1; d < 128; d <<= 1){
    int t = (tid >= d && tid < 128) ? off[tid-d] : 0;
    __syncthreads();
    if(tid < 128) off[tid] += t;
    __syncthreads();
  }
  if(tid < 128){
    int ex = off[tid] - v;            // exclusive prefix within bucket
    off[tid] = base + ex;             // global cursor for this node
    int node = (b << BKBITS) + tid;
    if(node < n){
      counts_c[node] = v;
      offsets[node]  = base + ex;
      dinv[node]     = rsqrtf(1.0f + (float)v);
    }
  }
  __syncthreads();
  for(int i = tid; i < cn; i += 256){
    uint32_t pk = p[i];
    int pos = atomicAdd(&off[pk >> 20], 1);
    csr_src[pos] = (int)(pk & 0xFFFFFu);
  }
}

// Wt1[n][k] = (bf16)W1[k][n] (256x128); Wt2[n][k] = (bf16)W2[k][n] (128x64). W* fp32.
__global__ void k_transpose(const float* __restrict__ W1, const float* __restrict__ W2,
                            bf16_t* __restrict__ Wt1, bf16_t* __restrict__ Wt2){
  int i = blockIdx.x*256 + threadIdx.x;
  if(i < 256*128){
    int k = i >> 7, nn = i & 127;
    Wt1[nn*256 + k] = (bf16_t)W1[i];
  } else {
    int j = i - 256*128;
    if(j < 128*64){
      int k = j >> 6, nn = j & 63;
      Wt2[nn*128 + k] = (bf16_t)W2[j];
    }
  }
}

// Raw A loads (issue early) + cast at use (keeps loads in flight; fp32->bf16 is VALU)
struct rawf { f32x4 u0, u1; };
static __device__ __forceinline__ rawf   load_raw(const float* __restrict__ p){
  return { *(const f32x4*)p, *(const f32x4*)(p + 4) };
}
static __device__ __forceinline__ bf16x8 load_raw(const bf16_t* __restrict__ p){
  return *(const bf16x8*)p;
}
static __device__ __forceinline__ bf16x8 to_frag(const rawf& r){
  bf16x8 o;
  o[0]=(bf16_t)r.u0[0]; o[1]=(bf16_t)r.u0[1]; o[2]=(bf16_t)r.u0[2]; o[3]=(bf16_t)r.u0[3];
  o[4]=(bf16_t)r.u1[0]; o[5]=(bf16_t)r.u1[1]; o[6]=(bf16_t)r.u1[2]; o[7]=(bf16_t)r.u1[3];
  return o;
}
static __device__ __forceinline__ bf16x8 to_frag(const bf16x8& r){ return r; }

// C[M,N](bf16) = scale[row] * (A[M,K] @ Bt^T). Bt is [N,K] bf16. A fp32 or bf16.
// B staged in LDS once per block (R2-R4 lesson: B re-reads thrash L1 and saturate
// the L2 request path). XOR swizzle slot^=row&(SLOTS-1): ds_read_b128 at the 2-way
// conflict floor. 8 waves x 32 rows = 256 rows/block; A streams with 1-step prefetch.
template<int K, int N, typename AT>
__global__ __launch_bounds__(512, 4) void k_gemm(const AT* __restrict__ A,
                                                 const bf16_t* __restrict__ Bt,
                                                 const float* __restrict__ scale,
                                                 bf16_t* __restrict__ C, int M){
  constexpr int NT = N/16;
  constexpr int NK = K/32;
  constexpr int SLOTS = K/8;        // 16B slots per B row
  constexpr int SM = SLOTS - 1;
  __shared__ bf16_t bs[N*K];        // 64KB (GEMM1) / 16KB (GEMM2)

  for(int i = threadIdx.x; i < N*K/8; i += 512){
    int n = i / SLOTS;
    int s = i & SM;
    bf16x8 v = *(const bf16x8*)(Bt + n*K + s*8);
    *(bf16x8*)&bs[n*K + ((s ^ (n & SM)))*8] = v;
  }
  __syncthreads();

  int lane = threadIdx.x & 63;
  int wave = threadIdx.x >> 6;
  int quad = lane >> 4;
  int m16  = lane & 15;
  long rbase = (long)blockIdx.x*256 + wave*32;
  long r0 = rbase + m16;        if(r0 > M-1) r0 = M-1;
  long r1 = rbase + 16 + m16;   if(r1 > M-1) r1 = M-1;

  f32x4 acc[2][NT];
  #pragma unroll
  for(int a = 0; a < 2; a++)
    #pragma unroll
    for(int t = 0; t < NT; t++) acc[a][t] = (f32x4){0.f,0.f,0.f,0.f};

  const AT* a0base = A + r0*K + quad*8;
  const AT* a1base = A + r1*K + quad*8;

  auto ra0 = load_raw(a0base);
  auto ra1 = load_raw(a1base);
  #pragma unroll
  for(int ks = 0; ks < NK; ks++){
    int kn = (ks+1 < NK) ? (ks+1)*32 : ks*32;   // last iter: redundant L1-hit reload
    auto rn0 = load_raw(a0base + kn);
    auto rn1 = load_raw(a1base + kn);
    bf16x8 a0 = to_frag(ra0);
    bf16x8 a1 = to_frag(ra1);
    bf16x8 b[NT];
    #pragma unroll
    for(int t = 0; t < NT; t++){
      int n = t*16 + m16;
      int swz = (ks*4 + quad) ^ (n & SM);
      b[t] = *(const bf16x8*)&bs[n*K + swz*8];
    }
    #pragma unroll
    for(int t = 0; t < NT; t++){
      acc[0][t] = __builtin_amdgcn_mfma_f32_16x16x32_bf16(a0, b[t], acc[0][t], 0, 0, 0);
      acc[1][t] = __builtin_amdgcn_mfma_f32_16x16x32_bf16(a1, b[t], acc[1][t], 0, 0, 0);
    }
    ra0 = rn0; ra1 = rn1;
  }

  // C/D layout: row = quad*4 + j, col = m16
  #pragma unroll
  for(int rt = 0; rt < 2; rt++){
    #pragma unroll
    for(int j = 0; j < 4; j++){
      long gr = rbase + rt*16 + quad*4 + j;
      if(gr < M){
        float sc = scale[gr];
        #pragma unroll
        for(int t = 0; t < NT; t++){
          C[gr*N + t*16 + m16] = (bf16_t)(sc * acc[rt][t][j]);
        }
      }
    }
  }
}

// hws is PRE-SCALED by dinv[row] (done in GEMM epilogue):
//   out[n][f0..f0+FW) = maybe_relu( dinv[n]*( sum hws[s][f0..] + hws[n][f0..] ) + b )
// FEATURE-SPLIT passes (R7 lesson: agg is bound on the L2-miss fill path, 53% hit
// at ws=25.6MB; halving the per-pass working set raises per-XCD L2 hit). NF = row
// stride, FW = features this pass. 16B/lane; EPI edges per wave-load; 16 edges/iter.
template<int NF, int FW, bool RELU, typename OT>
__global__ __launch_bounds__(256) void k_agg(const bf16_t* __restrict__ hws,
                                             const int* __restrict__ offsets,
                                             const int* __restrict__ counts,
                                             const int* __restrict__ csr_src,
                                             const float* __restrict__ dinv,
                                             const float* __restrict__ bias,
                                             OT* __restrict__ out, int n, int f0){
  constexpr int LPR = FW/8;      // lanes covering one row-slice, 8 feats (16B)/lane
  constexpr int EPI = 64/LPR;    // edges per wave-load
  constexpr int UNR = 16/EPI;    // 16 edges per loop iter
  int node = blockIdx.x*4 + (threadIdx.x >> 6);
  if(node >= n) return;
  int lane = threadIdx.x & 63;
  int h = lane / LPR;            // edge slot within the wave-load
  int c = lane % LPR;            // feature group: [f0 + c*8, f0 + c*8 + 8)
  int beg = offsets[node];
  int end = beg + counts[node];
  int last = end - 1;            // valid whenever the loop runs (end > beg)
  float dn = dinv[node];
  const bf16_t* hb = hws + f0 + c*8;

  float a0=0.f, a1=0.f, a2=0.f, a3=0.f, a4=0.f, a5=0.f, a6=0.f, a7=0.f;
  for(int e = beg; e < end; e += UNR*EPI){
    #pragma unroll
    for(int k = 0; k < UNR; k++){
      int idx = e + k*EPI + h;
      float m = (idx < end) ? 1.f : 0.f;
      int idxc = (idx < end) ? idx : last;     // clamped -> duplicate load, cache hit
      int s = csr_src[idxc];
      uint4 w = *(const uint4*)(hb + (long)s*NF);
      a0 = fmaf(m, bflo(w.x), a0); a1 = fmaf(m, bfhi(w.x), a1);
      a2 = fmaf(m, bflo(w.y), a2); a3 = fmaf(m, bfhi(w.y), a3);
      a4 = fmaf(m, bflo(w.z), a4); a5 = fmaf(m, bfhi(w.z), a5);
      a6 = fmaf(m, bflo(w.w), a6); a7 = fmaf(m, bfhi(w.w), a7);
    }
  }

  // reduce across edge slots
  #pragma unroll
  for(int d = LPR; d < 64; d <<= 1){
    a0 += __shfl_xor(a0, d); a1 += __shfl_xor(a1, d);
    a2 += __shfl_xor(a2, d); a3 += __shfl_xor(a3, d);
    a4 += __shfl_xor(a4, d); a5 += __shfl_xor(a5, d);
    a6 += __shfl_xor(a6, d); a7 += __shfl_xor(a7, d);
  }

  // self term (already dinv-scaled) + epilogue
  uint4 vs = *(const uint4*)(hb + (long)node*NF);
  a0 += bflo(vs.x); a1 += bfhi(vs.x); a2 += bflo(vs.y); a3 += bfhi(vs.y);
  a4 += bflo(vs.z); a5 += bfhi(vs.z); a6 += bflo(vs.w); a7 += bfhi(vs.w);
  f32x4 bv0 = *(const f32x4*)(bias + f0 + c*8);
  f32x4 bv1 = *(const f32x4*)(bias + f0 + c*8 + 4);
  a0 = fmaf(dn, a0, bv0[0]); a1 = fmaf(dn, a1, bv0[1]);
  a2 = fmaf(dn, a2, bv0[2]); a3 = fmaf(dn, a3, bv0[3]);
  a4 = fmaf(dn, a4, bv1[0]); a5 = fmaf(dn, a5, bv1[1]);
  a6 = fmaf(dn, a6, bv1[2]); a7 = fmaf(dn, a7, bv1[3]);
  if(RELU){
    a0=fmaxf(a0,0.f); a1=fmaxf(a1,0.f); a2=fmaxf(a2,0.f); a3=fmaxf(a3,0.f);
    a4=fmaxf(a4,0.f); a5=fmaxf(a5,0.f); a6=fmaxf(a6,0.f); a7=fmaxf(a7,0.f);
  }

  if(h == 0){
    if constexpr (sizeof(OT) == 2){
      union { bf16_t b[8]; uint4 u; } pk;
      pk.b[0]=(bf16_t)a0; pk.b[1]=(bf16_t)a1; pk.b[2]=(bf16_t)a2; pk.b[3]=(bf16_t)a3;
      pk.b[4]=(bf16_t)a4; pk.b[5]=(bf16_t)a5; pk.b[6]=(bf16_t)a6; pk.b[7]=(bf16_t)a7;
      *(uint4*)((bf16_t*)out + (long)node*NF + f0 + c*8) = pk.u;
    } else {
      f32x4 o0; o0[0]=a0; o0[1]=a1; o0[2]=a2; o0[3]=a3;
      f32x4 o1; o1[0]=a4; o1[1]=a5; o1[2]=a6; o1[3]=a7;
      *(f32x4*)((float*)out + (long)node*NF + f0 + c*8)     = o0;
      *(f32x4*)((float*)out + (long)node*NF + f0 + c*8 + 4) = o1;
    }
  }
}

extern "C" void kernel_launch(void* const* d_in, const int* in_sizes, int n_in,
                              void* d_out, int out_size, void* d_ws, size_t ws_size,
                              hipStream_t stream){
  // Verified model: x fp32 (100000,256); edge_index int32 (2,E) rows [src|dst];
  // W1/b1/W2/b2 fp32; OUTPUT fp32 (100000,64).
  const float* x  = (const float*)d_in[0];
  const int*   ei = (const int*)d_in[1];
  const float* W1 = (const float*)d_in[2];
  const float* b1 = (const float*)d_in[3];
  const float* W2 = (const float*)d_in[4];
  const float* b2 = (const float*)d_in[5];
  float* out = (float*)d_out;

  const int NN = in_sizes[0] / 256;   // 100000
  const int E  = in_sizes[1] / 2;     // 1600000
  const int nbk = (NN + 127) >> 7;    // 782 buckets

  char* ws = (char*)d_ws;
  size_t off = 0;
  auto alloc = [&](size_t bytes)->char*{
    char* p = ws + off;
    off = (off + bytes + 255) & ~(size_t)255;
    return p;
  };
  int*      bucketCursorP = (int*)     alloc((size_t)nbk*16*4);  // padded, 1/64B line
  int*      bucketBase    = (int*)     alloc((size_t)nbk*4);
  int*      counts_c      = (int*)     alloc((size_t)NN*4);
  int*      offsets       = (int*)     alloc((size_t)NN*4);
  float*    dinv          = (float*)   alloc((size_t)NN*4);
  uint32_t* pairs         = (uint32_t*)alloc((size_t)nbk*BKCAP*4);
  int*      csr_src       = (int*)     alloc((size_t)E*4);
  bf16_t*   Wt1           = (bf16_t*)  alloc(256*128*2);
  bf16_t*   Wt2           = (bf16_t*)  alloc(128*64*2);
  bf16_t*   hw1           = (bf16_t*)  alloc((size_t)NN*128*2);  // dinv-scaled x@W1
  bf16_t*   h1            = (bf16_t*)  alloc((size_t)NN*128*2);  // relu'd layer-1 out
  bf16_t*   hw2           = (bf16_t*)  alloc((size_t)NN*64*2);   // dinv-scaled h1@W2

  const int gblk = (NN + 255)/256;   // 391 blocks, 512 thr, 256 rows/block
  const int ablk = (NN + 3)/4;
  hipLaunchKernelGGL(k_zero_i,   dim3((nbk*16+255)/256), dim3(256), 0, stream, bucketCursorP, nbk*16);
  hipLaunchKernelGGL(k_bin,      dim3(256),  dim3(1024), 0, stream, ei, E, nbk, bucketCursorP, pairs);
  hipLaunchKernelGGL(k_scan_bkt, dim3(1),    dim3(1024), 0, stream, bucketCursorP, bucketBase, nbk);
  hipLaunchKernelGGL(k_fine,     dim3(nbk),  dim3(256),  0, stream, pairs, bucketCursorP, bucketBase,
                     counts_c, offsets, dinv, csr_src, NN);
  hipLaunchKernelGGL(k_transpose, dim3((256*128+128*64+255)/256), dim3(256), 0, stream, W1, W2, Wt1, Wt2);
  hipLaunchKernelGGL((k_gemm<256,128,float>), dim3(gblk), dim3(512), 0, stream, x, Wt1, dinv, hw1, NN);
  hipLaunchKernelGGL((k_agg<128,64,true,bf16_t>), dim3(ablk), dim3(256), 0, stream, hw1, offsets, counts_c, csr_src, dinv, b1, h1, NN, 0);
  hipLaunchKernelGGL((k_agg<128,64,true,bf16_t>), dim3(ablk), dim3(256), 0, stream, hw1, offsets, counts_c, csr_src, dinv, b1, h1, NN, 64);
  hipLaunchKernelGGL((k_gemm<128,64,bf16_t>), dim3(gblk), dim3(512), 0, stream, h1, Wt2, dinv, hw2, NN);
  hipLaunchKernelGGL((k_agg<64,32,false,float>), dim3(ablk), dim3(256), 0, stream, hw2, offsets, counts_c, csr_src, dinv, b2, out, NN, 0);
  hipLaunchKernelGGL((k_agg<64,32,false,float>), dim3(ablk), dim3(256), 0, stream, hw2, offsets, counts_c, csr_src, dinv, b2, out, NN, 32);
}

// Round 11
// 342.328 us; speedup vs baseline: 1.2048x; 1.2048x over previous
//
#include <hip/hip_runtime.h>
#include <stdint.h>

typedef __bf16 bf16_t;
typedef __bf16 bf16x8 __attribute__((ext_vector_type(8)));
typedef float f32x4 __attribute__((ext_vector_type(4)));

static __device__ __forceinline__ float bflo(uint32_t v){ union{uint32_t u; float f;} c; c.u = v<<16; return c.f; }
static __device__ __forceinline__ float bfhi(uint32_t v){ union{uint32_t u; float f;} c; c.u = v & 0xffff0000u; return c.f; }

#define BKBITS 7           // 128 nodes per bucket
#define MAXBK  1024        // supports NN <= 131072
#define BKCAP  3072        // slots per bucket (mean 2046, sd 45 -> +22 sd headroom)

// Setup: zero bucket cursors + weight transpose/cast (fused: saves a launch).
// Wt1[n][k] = (bf16)W1[k][n] (256x128); Wt2[n][k] = (bf16)W2[k][n] (128x64).
__global__ void k_setup(const float* __restrict__ W1, const float* __restrict__ W2,
                        bf16_t* __restrict__ Wt1, bf16_t* __restrict__ Wt2,
                        int* __restrict__ bucketCursorP, int nzero){
  int i = blockIdx.x*256 + threadIdx.x;
  if(i < nzero) bucketCursorP[i] = 0;
  if(i < 256*128){
    int k = i >> 7, nn = i & 127;
    Wt1[nn*256 + k] = (bf16_t)W1[i];
  } else {
    int j = i - 256*128;
    if(j < 128*64){
      int k = j >> 6, nn = j & 63;
      Wt2[nn*128 + k] = (bf16_t)W2[j];
    }
  }
}

// CSR build pass 1: bucket-binning. Per-block LDS histogram over dst>>7 buckets,
// ONE global atomic per (block,bucket) to reserve a range (200K fabric atomics
// instead of 1.6M - R5 lesson: fabric atomic-with-return caps at ~24 G/s),
// then LDS-cursor scatter of packed (src | dst_local<<20) into bucket segments.
// (R7-measured version: two-read loops; R9's register-cache variant unproven.)
__global__ __launch_bounds__(1024) void k_bin(const int* __restrict__ ei, int E, int nbk,
                                              int* __restrict__ bucketCursorP,
                                              uint32_t* __restrict__ pairs){
  __shared__ int hist[MAXBK];
  __shared__ int cur[MAXBK];
  int nb = gridDim.x;
  int per = (E + nb - 1) / nb;
  int e0 = blockIdx.x * per;
  int e1 = e0 + per; if(e1 > E) e1 = E;
  for(int i = threadIdx.x; i < nbk; i += 1024) hist[i] = 0;
  __syncthreads();
  for(int e = e0 + threadIdx.x; e < e1; e += 1024)
    atomicAdd(&hist[ei[E + e] >> BKBITS], 1);
  __syncthreads();
  for(int i = threadIdx.x; i < nbk; i += 1024){
    int h = hist[i];
    int base = h ? atomicAdd(&bucketCursorP[i << 4], h) : 0;
    cur[i] = i * BKCAP + base;
  }
  __syncthreads();
  for(int e = e0 + threadIdx.x; e < e1; e += 1024){
    int s = ei[e], d = ei[E + e];
    int b = d >> BKBITS;
    int pos = atomicAdd(&cur[b], 1);
    if(pos < (b + 1) * BKCAP)
      pairs[pos] = (uint32_t)s | ((uint32_t)(d & ((1<<BKBITS)-1)) << 20);
  }
}

// exclusive scan of bucket totals (padded cursors) -> bucketBase
__global__ __launch_bounds__(1024) void k_scan_bkt(const int* __restrict__ bucketCursorP,
                                                   int* __restrict__ bucketBase, int nbk){
  __shared__ int s[1024];
  int tid = threadIdx.x;
  int v = (tid < nbk) ? bucketCursorP[tid << 4] : 0;
  s[tid] = v; __syncthreads();
  #pragma unroll
  for(int d = 1; d < 1024; d <<= 1){
    int t = (tid >= d) ? s[tid-d] : 0;
    __syncthreads();
    s[tid] += t;
    __syncthreads();
  }
  if(tid < nbk) bucketBase[tid] = s[tid] - v;
}

// CSR build pass 2: one block per bucket. LDS count over 128 local nodes,
// LDS scan -> global offsets/counts/dinv, LDS-cursor scatter -> csr_src.
// All per-edge atomics are LDS. (R7-measured version.)
__global__ __launch_bounds__(256) void k_fine(const uint32_t* __restrict__ pairs,
                                              const int* __restrict__ bucketCursorP,
                                              const int* __restrict__ bucketBase,
                                              int* __restrict__ counts_c,
                                              int* __restrict__ offsets,
                                              float* __restrict__ dinv,
                                              int* __restrict__ csr_src, int n){
  __shared__ int cnt[128];
  __shared__ int off[128];
  int b = blockIdx.x;
  int cn = bucketCursorP[b << 4]; if(cn > BKCAP) cn = BKCAP;
  int base = bucketBase[b];
  const uint32_t* p = pairs + (long)b * BKCAP;
  int tid = threadIdx.x;
  if(tid < 128) cnt[tid] = 0;
  __syncthreads();
  for(int i = tid; i < cn; i += 256)
    atomicAdd(&cnt[p[i] >> 20], 1);
  __syncthreads();
  int v = (tid < 128) ? cnt[tid] : 0;
  if(tid < 128) off[tid] = v;
  __syncthreads();
  #pragma unroll
  for(int d = 1; d < 128; d <<= 1){
    int t = (tid >= d && tid < 128) ? off[tid-d] : 0;
    __syncthreads();
    if(tid < 128) off[tid] += t;
    __syncthreads();
  }
  if(tid < 128){
    int ex = off[tid] - v;            // exclusive prefix within bucket
    off[tid] = base + ex;             // global cursor for this node
    int node = (b << BKBITS) + tid;
    if(node < n){
      counts_c[node] = v;
      offsets[node]  = base + ex;
      dinv[node]     = rsqrtf(1.0f + (float)v);
    }
  }
  __syncthreads();
  for(int i = tid; i < cn; i += 256){
    uint32_t pk = p[i];
    int pos = atomicAdd(&off[pk >> 20], 1);
    csr_src[pos] = (int)(pk & 0xFFFFFu);
  }
}

// Raw A loads (issue early) + cast at use (keeps loads in flight; fp32->bf16 is VALU)
struct rawf { f32x4 u0, u1; };
static __device__ __forceinline__ rawf   load_raw(const float* __restrict__ p){
  return { *(const f32x4*)p, *(const f32x4*)(p + 4) };
}
static __device__ __forceinline__ bf16x8 load_raw(const bf16_t* __restrict__ p){
  return *(const bf16x8*)p;
}
static __device__ __forceinline__ bf16x8 to_frag(const rawf& r){
  bf16x8 o;
  o[0]=(bf16_t)r.u0[0]; o[1]=(bf16_t)r.u0[1]; o[2]=(bf16_t)r.u0[2]; o[3]=(bf16_t)r.u0[3];
  o[4]=(bf16_t)r.u1[0]; o[5]=(bf16_t)r.u1[1]; o[6]=(bf16_t)r.u1[2]; o[7]=(bf16_t)r.u1[3];
  return o;
}
static __device__ __forceinline__ bf16x8 to_frag(const bf16x8& r){ return r; }

// C[M,N](bf16) = scale[row] * (A[M,K] @ Bt^T). Bt is [N,K] bf16. A fp32 or bf16.
// B staged in LDS once per block (R2-R4 lesson: B re-reads thrash L1 and saturate
// the L2 request path). XOR swizzle slot^=row&(SLOTS-1): ds_read_b128 at the 2-way
// conflict floor. 8 waves x 32 rows = 256 rows/block; A streams with 1-step prefetch.
template<int K, int N, typename AT>
__global__ __launch_bounds__(512, 4) void k_gemm(const AT* __restrict__ A,
                                                 const bf16_t* __restrict__ Bt,
                                                 const float* __restrict__ scale,
                                                 bf16_t* __restrict__ C, int M){
  constexpr int NT = N/16;
  constexpr int NK = K/32;
  constexpr int SLOTS = K/8;        // 16B slots per B row
  constexpr int SM = SLOTS - 1;
  __shared__ bf16_t bs[N*K];        // 64KB (GEMM1) / 16KB (GEMM2)

  for(int i = threadIdx.x; i < N*K/8; i += 512){
    int n = i / SLOTS;
    int s = i & SM;
    bf16x8 v = *(const bf16x8*)(Bt + n*K + s*8);
    *(bf16x8*)&bs[n*K + ((s ^ (n & SM)))*8] = v;
  }
  __syncthreads();

  int lane = threadIdx.x & 63;
  int wave = threadIdx.x >> 6;
  int quad = lane >> 4;
  int m16  = lane & 15;
  long rbase = (long)blockIdx.x*256 + wave*32;
  long r0 = rbase + m16;        if(r0 > M-1) r0 = M-1;
  long r1 = rbase + 16 + m16;   if(r1 > M-1) r1 = M-1;

  f32x4 acc[2][NT];
  #pragma unroll
  for(int a = 0; a < 2; a++)
    #pragma unroll
    for(int t = 0; t < NT; t++) acc[a][t] = (f32x4){0.f,0.f,0.f,0.f};

  const AT* a0base = A + r0*K + quad*8;
  const AT* a1base = A + r1*K + quad*8;

  auto ra0 = load_raw(a0base);
  auto ra1 = load_raw(a1base);
  #pragma unroll
  for(int ks = 0; ks < NK; ks++){
    int kn = (ks+1 < NK) ? (ks+1)*32 : ks*32;   // last iter: redundant L1-hit reload
    auto rn0 = load_raw(a0base + kn);
    auto rn1 = load_raw(a1base + kn);
    bf16x8 a0 = to_frag(ra0);
    bf16x8 a1 = to_frag(ra1);
    bf16x8 b[NT];
    #pragma unroll
    for(int t = 0; t < NT; t++){
      int n = t*16 + m16;
      int swz = (ks*4 + quad) ^ (n & SM);
      b[t] = *(const bf16x8*)&bs[n*K + swz*8];
    }
    #pragma unroll
    for(int t = 0; t < NT; t++){
      acc[0][t] = __builtin_amdgcn_mfma_f32_16x16x32_bf16(a0, b[t], acc[0][t], 0, 0, 0);
      acc[1][t] = __builtin_amdgcn_mfma_f32_16x16x32_bf16(a1, b[t], acc[1][t], 0, 0, 0);
    }
    ra0 = rn0; ra1 = rn1;
  }

  // C/D layout: row = quad*4 + j, col = m16
  #pragma unroll
  for(int rt = 0; rt < 2; rt++){
    #pragma unroll
    for(int j = 0; j < 4; j++){
      long gr = rbase + rt*16 + quad*4 + j;
      if(gr < M){
        float sc = scale[gr];
        #pragma unroll
        for(int t = 0; t < NT; t++){
          C[gr*N + t*16 + m16] = (bf16_t)(sc * acc[rt][t][j]);
        }
      }
    }
  }
}

// hws is PRE-SCALED by dinv[row] (done in GEMM epilogue):
//   out[n] = maybe_relu( dinv[n]*( sum_{s in N(n)} hws[s] + hws[n] ) + bias )
// Wave per node, uint4 (16B) per lane: NF=128 -> 16 lanes/row, 4 edges/wave-load;
// NF=64 -> 8 lanes/row, 8 edges/wave-load. Full-width single pass (R8 lesson:
// feature-split doubles per-edge overhead without raising the L2/L3 fill hit rate).
template<int NF, bool RELU, typename OT>
__global__ __launch_bounds__(256) void k_agg(const bf16_t* __restrict__ hws,
                                             const int* __restrict__ offsets,
                                             const int* __restrict__ counts,
                                             const int* __restrict__ csr_src,
                                             const float* __restrict__ dinv,
                                             const float* __restrict__ bias,
                                             OT* __restrict__ out, int n){
  constexpr int LPR = NF/8;      // lanes covering one row, 8 feats (16B) per lane
  constexpr int EPI = 64/LPR;    // edges per wave-load
  constexpr int UNR = 16/EPI;    // 16 edges per loop iter
  int node = blockIdx.x*4 + (threadIdx.x >> 6);
  if(node >= n) return;
  int lane = threadIdx.x & 63;
  int h = lane / LPR;            // edge slot within the wave-load
  int c = lane % LPR;            // feature group: features [c*8, c*8+8)
  int beg = offsets[node];
  int end = beg + counts[node];
  int last = end - 1;            // valid whenever the loop runs (end > beg)
  float dn = dinv[node];

  float a0=0.f, a1=0.f, a2=0.f, a3=0.f, a4=0.f, a5=0.f, a6=0.f, a7=0.f;
  for(int e = beg; e < end; e += UNR*EPI){
    #pragma unroll
    for(int k = 0; k < UNR; k++){
      int idx = e + k*EPI + h;
      float m = (idx < end) ? 1.f : 0.f;
      int idxc = (idx < end) ? idx : last;     // clamped -> duplicate load, cache hit
      int s = csr_src[idxc];
      uint4 w = *(const uint4*)(hws + (long)s*NF + c*8);
      a0 = fmaf(m, bflo(w.x), a0); a1 = fmaf(m, bfhi(w.x), a1);
      a2 = fmaf(m, bflo(w.y), a2); a3 = fmaf(m, bfhi(w.y), a3);
      a4 = fmaf(m, bflo(w.z), a4); a5 = fmaf(m, bfhi(w.z), a5);
      a6 = fmaf(m, bflo(w.w), a6); a7 = fmaf(m, bfhi(w.w), a7);
    }
  }

  // reduce across edge slots
  #pragma unroll
  for(int d = LPR; d < 64; d <<= 1){
    a0 += __shfl_xor(a0, d); a1 += __shfl_xor(a1, d);
    a2 += __shfl_xor(a2, d); a3 += __shfl_xor(a3, d);
    a4 += __shfl_xor(a4, d); a5 += __shfl_xor(a5, d);
    a6 += __shfl_xor(a6, d); a7 += __shfl_xor(a7, d);
  }

  // self term (already dinv-scaled) + epilogue
  uint4 vs = *(const uint4*)(hws + (long)node*NF + c*8);
  a0 += bflo(vs.x); a1 += bfhi(vs.x); a2 += bflo(vs.y); a3 += bfhi(vs.y);
  a4 += bflo(vs.z); a5 += bfhi(vs.z); a6 += bflo(vs.w); a7 += bfhi(vs.w);
  f32x4 bv0 = *(const f32x4*)(bias + c*8);
  f32x4 bv1 = *(const f32x4*)(bias + c*8 + 4);
  a0 = fmaf(dn, a0, bv0[0]); a1 = fmaf(dn, a1, bv0[1]);
  a2 = fmaf(dn, a2, bv0[2]); a3 = fmaf(dn, a3, bv0[3]);
  a4 = fmaf(dn, a4, bv1[0]); a5 = fmaf(dn, a5, bv1[1]);
  a6 = fmaf(dn, a6, bv1[2]); a7 = fmaf(dn, a7, bv1[3]);
  if(RELU){
    a0=fmaxf(a0,0.f); a1=fmaxf(a1,0.f); a2=fmaxf(a2,0.f); a3=fmaxf(a3,0.f);
    a4=fmaxf(a4,0.f); a5=fmaxf(a5,0.f); a6=fmaxf(a6,0.f); a7=fmaxf(a7,0.f);
  }

  if(h == 0){
    if constexpr (sizeof(OT) == 2){
      union { bf16_t b[8]; uint4 u; } pk;
      pk.b[0]=(bf16_t)a0; pk.b[1]=(bf16_t)a1; pk.b[2]=(bf16_t)a2; pk.b[3]=(bf16_t)a3;
      pk.b[4]=(bf16_t)a4; pk.b[5]=(bf16_t)a5; pk.b[6]=(bf16_t)a6; pk.b[7]=(bf16_t)a7;
      *(uint4*)((bf16_t*)out + (long)node*NF + c*8) = pk.u;
    } else {
      f32x4 o0; o0[0]=a0; o0[1]=a1; o0[2]=a2; o0[3]=a3;
      f32x4 o1; o1[0]=a4; o1[1]=a5; o1[2]=a6; o1[3]=a7;
      *(f32x4*)((float*)out + (long)node*NF + c*8)     = o0;
      *(f32x4*)((float*)out + (long)node*NF + c*8 + 4) = o1;
    }
  }
}

extern "C" void kernel_launch(void* const* d_in, const int* in_sizes, int n_in,
                              void* d_out, int out_size, void* d_ws, size_t ws_size,
                              hipStream_t stream){
  // Verified model: x fp32 (100000,256); edge_index int32 (2,E) rows [src|dst];
  // W1/b1/W2/b2 fp32; OUTPUT fp32 (100000,64).
  const float* x  = (const float*)d_in[0];
  const int*   ei = (const int*)d_in[1];
  const float* W1 = (const float*)d_in[2];
  const float* b1 = (const float*)d_in[3];
  const float* W2 = (const float*)d_in[4];
  const float* b2 = (const float*)d_in[5];
  float* out = (float*)d_out;

  const int NN = in_sizes[0] / 256;   // 100000
  const int E  = in_sizes[1] / 2;     // 1600000
  const int nbk = (NN + 127) >> 7;    // 782 buckets

  char* ws = (char*)d_ws;
  size_t off = 0;
  auto alloc = [&](size_t bytes)->char*{
    char* p = ws + off;
    off = (off + bytes + 255) & ~(size_t)255;
    return p;
  };
  int*      bucketCursorP = (int*)     alloc((size_t)nbk*16*4);  // padded, 1/64B line
  int*      bucketBase    = (int*)     alloc((size_t)nbk*4);
  int*      counts_c      = (int*)     alloc((size_t)NN*4);
  int*      offsets       = (int*)     alloc((size_t)NN*4);
  float*    dinv          = (float*)   alloc((size_t)NN*4);
  uint32_t* pairs         = (uint32_t*)alloc((size_t)nbk*BKCAP*4);
  int*      csr_src       = (int*)     alloc((size_t)E*4);
  bf16_t*   Wt1           = (bf16_t*)  alloc(256*128*2);
  bf16_t*   Wt2           = (bf16_t*)  alloc(128*64*2);
  bf16_t*   hw1           = (bf16_t*)  alloc((size_t)NN*128*2);  // dinv-scaled x@W1
  bf16_t*   h1            = (bf16_t*)  alloc((size_t)NN*128*2);  // relu'd layer-1 out
  bf16_t*   hw2           = (bf16_t*)  alloc((size_t)NN*64*2);   // dinv-scaled h1@W2

  const int gblk = (NN + 255)/256;   // 391 blocks, 512 thr, 256 rows/block
  const int ablk = (NN + 3)/4;
  hipLaunchKernelGGL(k_setup,    dim3((256*128+128*64+255)/256), dim3(256), 0, stream,
                     W1, W2, Wt1, Wt2, bucketCursorP, nbk*16);
  hipLaunchKernelGGL(k_bin,      dim3(256),  dim3(1024), 0, stream, ei, E, nbk, bucketCursorP, pairs);
  hipLaunchKernelGGL(k_scan_bkt, dim3(1),    dim3(1024), 0, stream, bucketCursorP, bucketBase, nbk);
  hipLaunchKernelGGL(k_fine,     dim3(nbk),  dim3(256),  0, stream, pairs, bucketCursorP, bucketBase,
                     counts_c, offsets, dinv, csr_src, NN);
  hipLaunchKernelGGL((k_gemm<256,128,float>),  dim3(gblk), dim3(512), 0, stream, x,  Wt1, dinv, hw1, NN);
  hipLaunchKernelGGL((k_agg<128,true,bf16_t>), dim3(ablk), dim3(256), 0, stream, hw1, offsets, counts_c, csr_src, dinv, b1, h1, NN);
  hipLaunchKernelGGL((k_gemm<128,64,bf16_t>),  dim3(gblk), dim3(512), 0, stream, h1, Wt2, dinv, hw2, NN);
  hipLaunchKernelGGL((k_agg<64,false,float>),  dim3(ablk), dim3(256), 0, stream, hw2, offsets, counts_c, csr_src, dinv, b2, out, NN);
}